// Round 10
// baseline (336.386 us; speedup 1.0000x reference)
//
#include <hip/hip_runtime.h>
#include <hip/hip_bf16.h>

// MultiHeadAttention fused forward for MI355X (gfx950).
// B=2, S=2048, D=1024, H=16, DH=64. Outputs: out [B,S,D] fp32, attn [B,H,S,S] fp32.
static constexpr int cB = 2, cS = 2048, cD = 1024, cH = 16, cDH = 64;

typedef __attribute__((ext_vector_type(4))) float f32x4;
typedef __attribute__((ext_vector_type(8))) short s16x8;
typedef unsigned long long u64;
typedef unsigned short u16;

__device__ inline f32x4 mfma16(s16x8 a, s16x8 b, f32x4 c) {
  return __builtin_amdgcn_mfma_f32_16x16x32_bf16(a, b, c, 0, 0, 0);
}

// fp32 -> bf16 round-to-nearest-even (scalar)
__device__ inline u16 f2bf(float x) {
  unsigned u = __float_as_uint(x);
  u += 0x7FFFu + ((u >> 16) & 1u);
  return (u16)(u >> 16);
}

// packed fp32 pair -> bf16 pair (low = lo, high = hi), RTNE
__device__ inline unsigned cvt_pk_bf16(float lo, float hi) {
  unsigned r;
  asm("v_cvt_pk_bf16_f32 %0, %1, %2" : "=v"(r) : "v"(lo), "v"(hi));
  return r;
}

__device__ inline f32x4 zero4() { f32x4 z; z[0] = z[1] = z[2] = z[3] = 0.f; return z; }

// global -> LDS direct copy, 16 B per lane. dst is wave-uniform base + lane*16.
__device__ inline void gload16(const void* src, void* dst) {
  __builtin_amdgcn_global_load_lds((const __attribute__((address_space(1))) void*)src,
                                   (__attribute__((address_space(3))) void*)dst, 16, 0, 0);
}

// ---------------- 4x W transpose + bf16 convert (one launch) -------------------
__global__ __launch_bounds__(256) void wt4_kernel(const float* __restrict__ W0,
                                                  const float* __restrict__ W1,
                                                  const float* __restrict__ W2,
                                                  const float* __restrict__ W3,
                                                  u16* __restrict__ T0, u16* __restrict__ T1,
                                                  u16* __restrict__ T2, u16* __restrict__ T3) {
  __shared__ float tile[32][33];
  int z = blockIdx.z;
  const float* W = z == 0 ? W0 : z == 1 ? W1 : z == 2 ? W2 : W3;
  u16* Wt = z == 0 ? T0 : z == 1 ? T1 : z == 2 ? T2 : T3;
  int tx = threadIdx.x, ty = threadIdx.y;
  int r0 = blockIdx.y * 32, c0 = blockIdx.x * 32;
  for (int i = ty; i < 32; i += 8)
    tile[i][tx] = W[(size_t)(r0 + i) * cD + c0 + tx];
  __syncthreads();
  for (int i = ty; i < 32; i += 8)
    Wt[(size_t)(c0 + i) * cD + r0 + tx] = f2bf(tile[tx][i]);
}

// ---------------- mask nonzero bitmap: flag per (b, 64-row qtile, 64-col ktile) --
__global__ __launch_bounds__(256) void maskflag_kernel(const float* __restrict__ mask,
                                                       unsigned char* __restrict__ flags) {
  int blk = blockIdx.x;                       // b*1024 + qt*32 + kt
  int b = blk >> 10, qt = (blk >> 5) & 31, kt = blk & 31;
  int t = threadIdx.x;
  int r = t >> 2, c0 = (t & 3) * 16;
  const float4* p = (const float4*)(mask + ((size_t)b * cS + qt * 64 + r) * cS + kt * 64 + c0);
  int any = 0;
  for (int j = 0; j < 4; ++j) {
    float4 v = p[j];
    any |= (v.x != 0.f) | (v.y != 0.f) | (v.z != 0.f) | (v.w != 0.f);
  }
  __shared__ int sred;
  if (t == 0) sred = 0;
  __syncthreads();
  if (any) atomicOr(&sred, 1);
  __syncthreads();
  if (t == 0) flags[blk] = (unsigned char)sred;
}

// ---------------- 128xBN x64 GEMM body, 4 waves ---------------------------------
// LDS tiles are [rows][8 chunks of 16B], chunk XOR-swizzled by row&7 (staged via
// inverse-swizzled global source; read with matching swizzled ds_read_b128).
template<bool AFP32, bool OUTF32, int BN>
__device__ __forceinline__ void gemm_body(const void* __restrict__ Ap,
                                          const u16* __restrict__ Bt,
                                          const float* __restrict__ bias,
                                          void* __restrict__ outp,
                                          float scale, int vt_mode, int bidx,
                                          u16* As, u16* Bs) {
  constexpr int NI = BN / 32;   // 16x16 fragments per wave in N
  constexpr int RPW = BN / 4;   // B rows staged per wave
  int t = threadIdx.x;
  int w = t >> 6, l = t & 63, g = l >> 4, li = l & 15;
  int bm = bidx & 31, bn = bidx >> 5;
  int m0 = bm * 128, n0 = bn * BN;
  int wr = w >> 1, wc = w & 1;

  f32x4 acc[4][NI];
  for (int i = 0; i < 4; ++i)
    for (int j = 0; j < NI; ++j) acc[i][j] = zero4();

  for (int kk = 0; kk < cD; kk += 64) {
    if (AFP32) {
      const float* X = (const float*)Ap;
      int ar = t >> 1, ak0 = (t & 1) * 32;
      const float* asrc = X + (size_t)(m0 + ar) * cD + kk + ak0;
      int sw = ar & 7;
      for (int j = 0; j < 4; ++j) {
        float4 x0 = ((const float4*)asrc)[2 * j];
        float4 x1 = ((const float4*)asrc)[2 * j + 1];
        union { s16x8 v; unsigned u[4]; } s;
        s.u[0] = cvt_pk_bf16(x0.x, x0.y);
        s.u[1] = cvt_pk_bf16(x0.z, x0.w);
        s.u[2] = cvt_pk_bf16(x1.x, x1.y);
        s.u[3] = cvt_pk_bf16(x1.z, x1.w);
        int chunk = (ak0 >> 3) + j;
        *(s16x8*)&As[ar * 64 + ((chunk ^ sw) * 8)] = s.v;
      }
    } else {
      const u16* X = (const u16*)Ap;
      for (int is = 0; is < 4; ++is) {
        int row = w * 32 + is * 8 + (l >> 3);
        int chunk = l & 7;
        const u16* src = X + (size_t)(m0 + row) * cD + kk + ((chunk ^ (row & 7)) * 8);
        gload16(src, &As[(w * 32 + is * 8) * 64]);
      }
    }
    for (int is = 0; is < RPW / 8; ++is) {
      int row = w * RPW + is * 8 + (l >> 3);
      int chunk = l & 7;
      const u16* src = Bt + (size_t)(n0 + row) * cD + kk + ((chunk ^ (row & 7)) * 8);
      gload16(src, &Bs[(w * RPW + is * 8) * 64]);
    }
    __syncthreads();
    for (int c = 0; c < 2; ++c) {
      s16x8 af[4], bf[NI];
      for (int mi = 0; mi < 4; ++mi) {
        int r = wr * 64 + mi * 16 + li;
        af[mi] = *(const s16x8*)&As[r * 64 + (((c * 4 + g) ^ (r & 7)) * 8)];
      }
      for (int ni = 0; ni < NI; ++ni) {
        int r = wc * (BN / 2) + ni * 16 + li;
        bf[ni] = *(const s16x8*)&Bs[r * 64 + (((c * 4 + g) ^ (r & 7)) * 8)];
      }
      for (int mi = 0; mi < 4; ++mi)
        for (int ni = 0; ni < NI; ++ni)
          acc[mi][ni] = mfma16(af[mi], bf[ni], acc[mi][ni]);
    }
    __syncthreads();
  }

  for (int ni = 0; ni < NI; ++ni) {
    int n = n0 + wc * (BN / 2) + ni * 16 + li;
    float bv = bias[n];
    for (int mi = 0; mi < 4; ++mi) {
      for (int r = 0; r < 4; ++r) {
        int m = m0 + wr * 64 + mi * 16 + g * 4 + r;
        float val = acc[mi][ni][r] + bv;
        if (OUTF32) {
          ((float*)outp)[(size_t)m * cD + n] = val;
        } else {
          val *= scale;
          int b = m >> 11, s = m & 2047;
          int h = n >> 6, d = n & 63;
          size_t idx = vt_mode ? ((size_t)(b * cH + h) * cDH + d) * cS + s
                               : ((size_t)(b * cH + h) * cS + s) * cDH + d;
          ((u16*)outp)[idx] = f2bf(val);
        }
      }
    }
  }
}

// fused Q/K/V projection: 768 blocks = 3 x 256 (matrix selected by blockIdx>>8)
__global__ __launch_bounds__(256) void qkv_gemm(const float* __restrict__ Xq,
                                                const float* __restrict__ Xk,
                                                const float* __restrict__ Xv,
                                                const u16* __restrict__ Btq,
                                                const u16* __restrict__ Btk,
                                                const u16* __restrict__ Btv,
                                                const float* __restrict__ bq,
                                                const float* __restrict__ bk,
                                                const float* __restrict__ bv,
                                                u16* __restrict__ oq,
                                                u16* __restrict__ ok,
                                                u16* __restrict__ ov) {
  __shared__ __attribute__((aligned(16))) u16 As[128 * 64];
  __shared__ __attribute__((aligned(16))) u16 Bs[128 * 64];
  int which = blockIdx.x >> 8, bidx = blockIdx.x & 255;
  const float* X = which == 0 ? Xq : which == 1 ? Xk : Xv;
  const u16* Bt = which == 0 ? Btq : which == 1 ? Btk : Btv;
  const float* bias = which == 0 ? bq : which == 1 ? bk : bv;
  u16* o = which == 0 ? oq : which == 1 ? ok : ov;
  float scale = which == 0 ? 0.125f : 1.0f;   // Q pre-scaled by 1/sqrt(DH)
  int vt = which == 2 ? 1 : 0;
  gemm_body<true, false, 128>(X, Bt, bias, o, scale, vt, bidx, As, Bs);
}

// output GEMM: 128x64 tile -> 512 blocks (2 blocks/CU)
__global__ __launch_bounds__(256) void out_gemm(const u16* __restrict__ Xc,
                                                const u16* __restrict__ Bt,
                                                const float* __restrict__ bias,
                                                float* __restrict__ outp) {
  __shared__ __attribute__((aligned(16))) u16 As[128 * 64];
  __shared__ __attribute__((aligned(16))) u16 Bs[64 * 64];
  gemm_body<false, true, 64>(Xc, Bt, bias, outp, 1.0f, 0, blockIdx.x, As, Bs);
}

// ---------------- fused attention: dbuf + raw barrier + counted vmcnt ----------
// Grid: B*H*(S/128) = 512 blocks (XCD-swizzled), 512 threads = 8 waves, 16 q-rows
// per wave. Swapped QK^T: mfma(K,Q) -> lane li owns q-row li; P in registers;
// attn stored as nontemporal float4 with normalization folded into the exponent.
// K/V tiles (64x64) double-buffered via global_load_lds (chunk XOR-swizzle),
// ONE raw s_barrier per kt with counted vmcnt: pass B uses vmcnt(4) so the 4
// attn stores stay in flight across the barrier (never drained in-loop).
// Fragment k-maps (A/B identical per MFMA):
//   QK^T: dh = c*32 + 8g + e            (one 16B LDS read per fragment)
//   PV:   k  = c*32 + h*16 + 4g + r     (two 8B LDS reads), frag elem e = h*4+r
__global__ __launch_bounds__(512) void attn_kernel(const u16* __restrict__ Q,
                                                   const u16* __restrict__ K,
                                                   const u16* __restrict__ Vt,
                                                   const float* __restrict__ mask,
                                                   const unsigned char* __restrict__ flags,
                                                   float* __restrict__ attn,
                                                   u16* __restrict__ ctx) {
  __shared__ __attribute__((aligned(16))) u16 Kl[2][64 * 64];
  __shared__ __attribute__((aligned(16))) u16 Vl[2][64 * 64];
  int t = threadIdx.x;
  int w = t >> 6, l = t & 63, g = l >> 4, li = l & 15;
  int p = blockIdx.x;
  int blk = (p & 7) * 64 + (p >> 3);    // XCD-contiguous: XCD x gets bh 4x..4x+3
  int bh = blk >> 4, qt = blk & 15;
  int b = bh >> 4;
  int qbase = qt * 128;
  const u16* Qh = Q + (size_t)bh * cS * cDH;
  const u16* Kh = K + (size_t)bh * cS * cDH;
  const u16* Vh = Vt + (size_t)bh * cDH * cS;
  // flags are per 64-row q-tile; this wave's rows live in one 64-tile
  const unsigned char* fl = flags + (b << 10) + ((qbase + w * 16) >> 6) * 32;

  // Q fragments (pre-scaled by 1/8), MFMA B operand
  s16x8 qf[2];
  {
    const u16* qp = Qh + (size_t)(qbase + w * 16 + li) * cDH;
    qf[0] = *(const s16x8*)(qp + 8 * g);
    qf[1] = *(const s16x8*)(qp + 32 + 8 * g);
  }
  int srow8 = l >> 3, schunk = l & 7;
  int q_lane = qbase + w * 16 + li;
  int srow = w * 8 + srow8;                       // this lane's staged row
  const u16* kstage = Kh + (size_t)srow * cDH + ((schunk ^ (srow & 7)) * 8);
  const u16* vstage = Vh + (size_t)srow * cS + ((schunk ^ (srow & 7)) * 8);
  u16* kl_dst = &Kl[0][(w * 8) * 64];             // wave-uniform LDS bases
  u16* vl_dst = &Vl[0][(w * 8) * 64];
  const int KSTEP = 64 * cDH;                     // K elems per kt

  // ---- Pass A: row sums of exp(logits); K double-buffered, 1 barrier/kt ----
  gload16(kstage, kl_dst);
  asm volatile("s_waitcnt vmcnt(0)" ::: "memory");
  __builtin_amdgcn_sched_barrier(0);
  __builtin_amdgcn_s_barrier();
  __builtin_amdgcn_sched_barrier(0);
  float racc4[4] = {0.f, 0.f, 0.f, 0.f};         // 4 independent chains
  for (int kt = 0; kt < 32; ++kt) {
    int cur = kt & 1;
    if (kt + 1 < 32)
      gload16(kstage + (size_t)(kt + 1) * KSTEP, kl_dst + (cur ^ 1) * 64 * 64);
    f32x4 acc[4];
    for (int mt = 0; mt < 4; ++mt) acc[mt] = zero4();
    for (int c = 0; c < 2; ++c)
      for (int mt = 0; mt < 4; ++mt) {
        int r = mt * 16 + li;
        s16x8 kf = *(const s16x8*)&Kl[cur][r * 64 + (((c * 4 + g) ^ (r & 7)) * 8)];
        acc[mt] = mfma16(kf, qf[c], acc[mt]);
      }
    bool um = fl[kt] != 0;
    for (int mt = 0; mt < 4; ++mt)
      for (int r = 0; r < 4; ++r) {
        float lv = acc[mt][r];
        if (um) lv += mask[((size_t)b * cS + q_lane) * cS + kt * 64 + mt * 16 + 4 * g + r] * -1e9f;
        racc4[r] += __expf(lv);
      }
    if (kt + 1 < 32) {
      asm volatile("s_waitcnt vmcnt(0)" ::: "memory");
      __builtin_amdgcn_sched_barrier(0);
      __builtin_amdgcn_s_barrier();
      __builtin_amdgcn_sched_barrier(0);
    }
  }
  float racc = (racc4[0] + racc4[1]) + (racc4[2] + racc4[3]);
  racc += __shfl_xor(racc, 16, 64);
  racc += __shfl_xor(racc, 32, 64);
  float lr = __logf(racc);   // log denominator: p = exp(lv - lr)

  // ---- Pass B: K/V double-buffered; stores stay in flight across barriers ----
  f32x4 cacc[4];
  for (int dt = 0; dt < 4; ++dt) cacc[dt] = zero4();
  float* attn_row = attn + (size_t)bh * cS * cS + (size_t)q_lane * cS;
  gload16(kstage, kl_dst);
  gload16(vstage, vl_dst);
  asm volatile("s_waitcnt vmcnt(0)" ::: "memory");
  __builtin_amdgcn_sched_barrier(0);
  __builtin_amdgcn_s_barrier();
  __builtin_amdgcn_sched_barrier(0);
  for (int kt = 0; kt < 32; ++kt) {
    int cur = kt & 1;
    if (kt + 1 < 32) {
      gload16(kstage + (size_t)(kt + 1) * KSTEP, kl_dst + (cur ^ 1) * 64 * 64);
      gload16(vstage + (kt + 1) * 64, vl_dst + (cur ^ 1) * 64 * 64);
    }
    f32x4 acc[4];
    for (int mt = 0; mt < 4; ++mt) acc[mt] = zero4();
    for (int c = 0; c < 2; ++c)
      for (int mt = 0; mt < 4; ++mt) {
        int r = mt * 16 + li;
        s16x8 kf = *(const s16x8*)&Kl[cur][r * 64 + (((c * 4 + g) ^ (r & 7)) * 8)];
        acc[mt] = mfma16(kf, qf[c], acc[mt]);
      }
    bool um = fl[kt] != 0;
    s16x8 pa[2];
    for (int c = 0; c < 2; ++c) {
      union { s16x8 v; unsigned u[4]; } pk;
      f32x4 pvq[2];
      for (int hh = 0; hh < 2; ++hh) {
        int mt = c * 2 + hh;
        for (int r = 0; r < 4; ++r) {
          float lv = acc[mt][r];
          if (um) lv += mask[((size_t)b * cS + q_lane) * cS + kt * 64 + mt * 16 + 4 * g + r] * -1e9f;
          pvq[hh][r] = __expf(lv - lr);
        }
        __builtin_nontemporal_store(pvq[hh], (f32x4*)(attn_row + kt * 64 + mt * 16 + 4 * g));
      }
      pk.u[0] = cvt_pk_bf16(pvq[0][0], pvq[0][1]);
      pk.u[1] = cvt_pk_bf16(pvq[0][2], pvq[0][3]);
      pk.u[2] = cvt_pk_bf16(pvq[1][0], pvq[1][1]);
      pk.u[3] = cvt_pk_bf16(pvq[1][2], pvq[1][3]);
      pa[c] = pk.v;
    }
    // PV: B-operand V fragments from LDS (row d = dt*16+li), same k-map as P
    for (int c = 0; c < 2; ++c) {
      for (int dt = 0; dt < 4; ++dt) {
        int row = dt * 16 + li;
        const u16* rb = &Vl[cur][row * 64];
        int o0 = (((c * 4 + 0 + (g >> 1)) ^ (li & 7)) * 8) + (g & 1) * 4;
        int o1 = (((c * 4 + 2 + (g >> 1)) ^ (li & 7)) * 8) + (g & 1) * 4;
        union { s16x8 v; u64 qq[2]; } vf;
        vf.qq[0] = *(const u64*)(rb + o0);
        vf.qq[1] = *(const u64*)(rb + o1);
        cacc[dt] = mfma16(pa[c], vf.v, cacc[dt]);
      }
    }
    if (kt + 1 < 32) {
      // wait for the 2 prefetch gloads (older) while the 4 attn stores
      // (younger) remain in flight across the barrier
      asm volatile("s_waitcnt vmcnt(4)" ::: "memory");
      __builtin_amdgcn_sched_barrier(0);
      __builtin_amdgcn_s_barrier();
      __builtin_amdgcn_sched_barrier(0);
    }
  }

  // ctx -> concat layout [b*S+s][h*64+d] bf16 for the output GEMM
  int h = bh & 15;
  for (int dt = 0; dt < 4; ++dt)
    for (int r = 0; r < 4; ++r) {
      int s = qbase + w * 16 + g * 4 + r;
      int d = dt * 16 + li;
      ctx[((size_t)(b * cS + s)) * cD + h * 64 + d] = f2bf(cacc[dt][r]);
    }
}

// ---------------- host launch --------------------------------------------------
extern "C" void kernel_launch(void* const* d_in, const int* in_sizes, int n_in,
                              void* d_out, int out_size, void* d_ws, size_t ws_size,
                              hipStream_t stream) {
  const float* q_in = (const float*)d_in[0];
  const float* k_in = (const float*)d_in[1];
  const float* v_in = (const float*)d_in[2];
  const float* mask = (const float*)d_in[3];
  const float* Wq = (const float*)d_in[4];
  const float* bq = (const float*)d_in[5];
  const float* Wk = (const float*)d_in[6];
  const float* bk = (const float*)d_in[7];
  const float* Wv = (const float*)d_in[8];
  const float* bv = (const float*)d_in[9];
  const float* Wo = (const float*)d_in[10];
  const float* bo = (const float*)d_in[11];

  float* out = (float*)d_out;                       // [B,S,D]
  float* attn = out + (size_t)cB * cS * cD;         // [B,H,S,S]

  // workspace layout (bf16 = 2B): 4 W^T (8MB) + Q + K + Vt + ctx (8MB ea) + flags
  const size_t MATB = (size_t)cB * cS * cD * 2;     // 8,388,608 B
  const size_t WB = (size_t)cD * cD * 2;            // 2,097,152 B
  char* ws = (char*)d_ws;
  u16* WqT = (u16*)(ws);
  u16* WkT = (u16*)(ws + WB);
  u16* WvT = (u16*)(ws + 2 * WB);
  u16* WoT = (u16*)(ws + 3 * WB);
  u16* wsQ  = (u16*)(ws + 4 * WB);
  u16* wsK  = (u16*)(ws + 4 * WB + MATB);
  u16* wsVt = (u16*)(ws + 4 * WB + 2 * MATB);
  u16* wsC  = (u16*)(ws + 4 * WB + 3 * MATB);
  unsigned char* flags = (unsigned char*)(ws + 4 * WB + 4 * MATB);
  const size_t REQUIRED = 4 * WB + 4 * MATB + 2048;
  if (ws_size < REQUIRED) return;  // loud failure (validation will catch)

  dim3 tb(32, 8);
  wt4_kernel<<<dim3(32, 32, 4), tb, 0, stream>>>(Wq, Wk, Wv, Wo, WqT, WkT, WvT, WoT);
  maskflag_kernel<<<2048, 256, 0, stream>>>(mask, flags);

  qkv_gemm<<<768, 256, 0, stream>>>(q_in, k_in, v_in, WqT, WkT, WvT,
                                    bq, bk, bv, wsQ, wsK, wsVt);

  attn_kernel<<<512, 512, 0, stream>>>(wsQ, wsK, wsVt, mask, flags, attn, wsC);

  out_gemm<<<512, 256, 0, stream>>>(wsC, WoT, bo, out);
}

// Round 11
// 326.450 us; speedup vs baseline: 1.0304x; 1.0304x over previous
//
#include <hip/hip_runtime.h>
#include <hip/hip_bf16.h>

// MultiHeadAttention fused forward for MI355X (gfx950).
// B=2, S=2048, D=1024, H=16, DH=64. Outputs: out [B,S,D] fp32, attn [B,H,S,S] fp32.
static constexpr int cB = 2, cS = 2048, cD = 1024, cH = 16, cDH = 64;

typedef __attribute__((ext_vector_type(4))) float f32x4;
typedef __attribute__((ext_vector_type(8))) short s16x8;
typedef unsigned long long u64;
typedef unsigned short u16;

__device__ inline f32x4 mfma16(s16x8 a, s16x8 b, f32x4 c) {
  return __builtin_amdgcn_mfma_f32_16x16x32_bf16(a, b, c, 0, 0, 0);
}

// fp32 -> bf16 round-to-nearest-even (scalar)
__device__ inline u16 f2bf(float x) {
  unsigned u = __float_as_uint(x);
  u += 0x7FFFu + ((u >> 16) & 1u);
  return (u16)(u >> 16);
}

// packed fp32 pair -> bf16 pair (low = lo, high = hi), RTNE
__device__ inline unsigned cvt_pk_bf16(float lo, float hi) {
  unsigned r;
  asm("v_cvt_pk_bf16_f32 %0, %1, %2" : "=v"(r) : "v"(lo), "v"(hi));
  return r;
}

__device__ inline f32x4 zero4() { f32x4 z; z[0] = z[1] = z[2] = z[3] = 0.f; return z; }

// global -> LDS direct copy, 16 B per lane. dst is wave-uniform base + lane*16.
__device__ inline void gload16(const void* src, void* dst) {
  __builtin_amdgcn_global_load_lds((const __attribute__((address_space(1))) void*)src,
                                   (__attribute__((address_space(3))) void*)dst, 16, 0, 0);
}

// ---------------- fp32 -> bf16 bulk convert (X inputs for the GEMMs) -----------
// Each thread converts 8 elems. Grid: (elems/8/256) x 1 x 3 matrices.
__global__ __launch_bounds__(256) void xcvt_kernel(const float* __restrict__ X0,
                                                   const float* __restrict__ X1,
                                                   const float* __restrict__ X2,
                                                   u16* __restrict__ Y0,
                                                   u16* __restrict__ Y1,
                                                   u16* __restrict__ Y2) {
  int z = blockIdx.z;
  const float* X = z == 0 ? X0 : z == 1 ? X1 : X2;
  u16* Y = z == 0 ? Y0 : z == 1 ? Y1 : Y2;
  size_t i = ((size_t)blockIdx.x * 256 + threadIdx.x) * 8;
  float4 a = *(const float4*)(X + i);
  float4 b = *(const float4*)(X + i + 4);
  union { s16x8 v; unsigned u[4]; } s;
  s.u[0] = cvt_pk_bf16(a.x, a.y);
  s.u[1] = cvt_pk_bf16(a.z, a.w);
  s.u[2] = cvt_pk_bf16(b.x, b.y);
  s.u[3] = cvt_pk_bf16(b.z, b.w);
  *(s16x8*)(Y + i) = s.v;
}

// ---------------- 4x W transpose + bf16 convert (one launch) -------------------
__global__ __launch_bounds__(256) void wt4_kernel(const float* __restrict__ W0,
                                                  const float* __restrict__ W1,
                                                  const float* __restrict__ W2,
                                                  const float* __restrict__ W3,
                                                  u16* __restrict__ T0, u16* __restrict__ T1,
                                                  u16* __restrict__ T2, u16* __restrict__ T3) {
  __shared__ float tile[32][33];
  int z = blockIdx.z;
  const float* W = z == 0 ? W0 : z == 1 ? W1 : z == 2 ? W2 : W3;
  u16* Wt = z == 0 ? T0 : z == 1 ? T1 : z == 2 ? T2 : T3;
  int tx = threadIdx.x, ty = threadIdx.y;
  int r0 = blockIdx.y * 32, c0 = blockIdx.x * 32;
  for (int i = ty; i < 32; i += 8)
    tile[i][tx] = W[(size_t)(r0 + i) * cD + c0 + tx];
  __syncthreads();
  for (int i = ty; i < 32; i += 8)
    Wt[(size_t)(c0 + i) * cD + r0 + tx] = f2bf(tile[tx][i]);
}

// ---------------- mask nonzero bitmap: flag per (b, 64-row qtile, 64-col ktile) --
__global__ __launch_bounds__(256) void maskflag_kernel(const float* __restrict__ mask,
                                                       unsigned char* __restrict__ flags) {
  int blk = blockIdx.x;                       // b*1024 + qt*32 + kt
  int b = blk >> 10, qt = (blk >> 5) & 31, kt = blk & 31;
  int t = threadIdx.x;
  int r = t >> 2, c0 = (t & 3) * 16;
  const float4* p = (const float4*)(mask + ((size_t)b * cS + qt * 64 + r) * cS + kt * 64 + c0);
  int any = 0;
  for (int j = 0; j < 4; ++j) {
    float4 v = p[j];
    any |= (v.x != 0.f) | (v.y != 0.f) | (v.z != 0.f) | (v.w != 0.f);
  }
  __shared__ int sred;
  if (t == 0) sred = 0;
  __syncthreads();
  if (any) atomicOr(&sred, 1);
  __syncthreads();
  if (t == 0) flags[blk] = (unsigned char)sred;
}

// ---------------- 128xBN x64 GEMM body, 4 waves, bf16 A and B -------------------
// LDS tiles are [rows][8 chunks of 16B], chunk XOR-swizzled by row&7 (staged via
// inverse-swizzled global source; read with matching swizzled ds_read_b128).
template<bool OUTF32, int BN>
__device__ __forceinline__ void gemm_body(const u16* __restrict__ X,
                                          const u16* __restrict__ Bt,
                                          const float* __restrict__ bias,
                                          void* __restrict__ outp,
                                          float scale, int vt_mode, int bidx,
                                          u16* As, u16* Bs) {
  constexpr int NI = BN / 32;   // 16x16 fragments per wave in N
  constexpr int RPW = BN / 4;   // B rows staged per wave
  int t = threadIdx.x;
  int w = t >> 6, l = t & 63, g = l >> 4, li = l & 15;
  int bm = bidx & 31, bn = bidx >> 5;
  int m0 = bm * 128, n0 = bn * BN;
  int wr = w >> 1, wc = w & 1;

  f32x4 acc[4][NI];
  for (int i = 0; i < 4; ++i)
    for (int j = 0; j < NI; ++j) acc[i][j] = zero4();

  for (int kk = 0; kk < cD; kk += 64) {
    for (int is = 0; is < 4; ++is) {
      int row = w * 32 + is * 8 + (l >> 3);
      int chunk = l & 7;
      const u16* src = X + (size_t)(m0 + row) * cD + kk + ((chunk ^ (row & 7)) * 8);
      gload16(src, &As[(w * 32 + is * 8) * 64]);
    }
    for (int is = 0; is < RPW / 8; ++is) {
      int row = w * RPW + is * 8 + (l >> 3);
      int chunk = l & 7;
      const u16* src = Bt + (size_t)(n0 + row) * cD + kk + ((chunk ^ (row & 7)) * 8);
      gload16(src, &Bs[(w * RPW + is * 8) * 64]);
    }
    __syncthreads();
    for (int c = 0; c < 2; ++c) {
      s16x8 af[4], bf[NI];
      for (int mi = 0; mi < 4; ++mi) {
        int r = wr * 64 + mi * 16 + li;
        af[mi] = *(const s16x8*)&As[r * 64 + (((c * 4 + g) ^ (r & 7)) * 8)];
      }
      for (int ni = 0; ni < NI; ++ni) {
        int r = wc * (BN / 2) + ni * 16 + li;
        bf[ni] = *(const s16x8*)&Bs[r * 64 + (((c * 4 + g) ^ (r & 7)) * 8)];
      }
      for (int mi = 0; mi < 4; ++mi)
        for (int ni = 0; ni < NI; ++ni)
          acc[mi][ni] = mfma16(af[mi], bf[ni], acc[mi][ni]);
    }
    __syncthreads();
  }

  for (int ni = 0; ni < NI; ++ni) {
    int n = n0 + wc * (BN / 2) + ni * 16 + li;
    float bv = bias[n];
    for (int mi = 0; mi < 4; ++mi) {
      for (int r = 0; r < 4; ++r) {
        int m = m0 + wr * 64 + mi * 16 + g * 4 + r;
        float val = acc[mi][ni][r] + bv;
        if (OUTF32) {
          ((float*)outp)[(size_t)m * cD + n] = val;
        } else {
          val *= scale;
          int b = m >> 11, s = m & 2047;
          int h = n >> 6, d = n & 63;
          size_t idx = vt_mode ? ((size_t)(b * cH + h) * cDH + d) * cS + s
                               : ((size_t)(b * cH + h) * cS + s) * cDH + d;
          ((u16*)outp)[idx] = f2bf(val);
        }
      }
    }
  }
}

// fused Q/K/V projection: 768 blocks = 3 x 256 (matrix selected by blockIdx>>8)
__global__ __launch_bounds__(256) void qkv_gemm(const u16* __restrict__ Xq,
                                                const u16* __restrict__ Xk,
                                                const u16* __restrict__ Xv,
                                                const u16* __restrict__ Btq,
                                                const u16* __restrict__ Btk,
                                                const u16* __restrict__ Btv,
                                                const float* __restrict__ bq,
                                                const float* __restrict__ bk,
                                                const float* __restrict__ bv,
                                                u16* __restrict__ oq,
                                                u16* __restrict__ ok,
                                                u16* __restrict__ ov) {
  __shared__ __attribute__((aligned(16))) u16 As[128 * 64];
  __shared__ __attribute__((aligned(16))) u16 Bs[128 * 64];
  int which = blockIdx.x >> 8, bidx = blockIdx.x & 255;
  const u16* X = which == 0 ? Xq : which == 1 ? Xk : Xv;
  const u16* Bt = which == 0 ? Btq : which == 1 ? Btk : Btv;
  const float* bias = which == 0 ? bq : which == 1 ? bk : bv;
  u16* o = which == 0 ? oq : which == 1 ? ok : ov;
  float scale = which == 0 ? 0.125f : 1.0f;   // Q pre-scaled by 1/sqrt(DH)
  int vt = which == 2 ? 1 : 0;
  gemm_body<false, 128>(X, Bt, bias, o, scale, vt, bidx, As, Bs);
}

// output GEMM: 128x64 tile -> 512 blocks (2 blocks/CU)
__global__ __launch_bounds__(256) void out_gemm(const u16* __restrict__ Xc,
                                                const u16* __restrict__ Bt,
                                                const float* __restrict__ bias,
                                                float* __restrict__ outp) {
  __shared__ __attribute__((aligned(16))) u16 As[128 * 64];
  __shared__ __attribute__((aligned(16))) u16 Bs[64 * 64];
  gemm_body<true, 64>(Xc, Bt, bias, outp, 1.0f, 0, blockIdx.x, As, Bs);
}

// ---------------- fused attention: dbuf + raw barrier + counted vmcnt ----------
// Grid: B*H*(S/128) = 512 blocks (XCD-swizzled), 512 threads = 8 waves, 16 q-rows
// per wave. Swapped QK^T: mfma(K,Q) -> lane li owns q-row li; P in registers;
// attn stored as plain float4 (NT removed: suspect for partial-line behavior)
// with normalization folded into the exponent. K/V tiles (64x64) double-buffered
// via global_load_lds (chunk XOR-swizzle), one raw s_barrier per kt; pass B
// waits vmcnt(4) so the 4 attn stores stay in flight across the barrier.
// Fragment k-maps (A/B identical per MFMA):
//   QK^T: dh = c*32 + 8g + e            (one 16B LDS read per fragment)
//   PV:   k  = c*32 + h*16 + 4g + r     (two 8B LDS reads), frag elem e = h*4+r
__global__ __launch_bounds__(512) void attn_kernel(const u16* __restrict__ Q,
                                                   const u16* __restrict__ K,
                                                   const u16* __restrict__ Vt,
                                                   const float* __restrict__ mask,
                                                   const unsigned char* __restrict__ flags,
                                                   float* __restrict__ attn,
                                                   u16* __restrict__ ctx) {
  __shared__ __attribute__((aligned(16))) u16 Kl[2][64 * 64];
  __shared__ __attribute__((aligned(16))) u16 Vl[2][64 * 64];
  int t = threadIdx.x;
  int w = t >> 6, l = t & 63, g = l >> 4, li = l & 15;
  int p = blockIdx.x;
  int blk = (p & 7) * 64 + (p >> 3);    // XCD-contiguous: XCD x gets bh 4x..4x+3
  int bh = blk >> 4, qt = blk & 15;
  int b = bh >> 4;
  int qbase = qt * 128;
  const u16* Qh = Q + (size_t)bh * cS * cDH;
  const u16* Kh = K + (size_t)bh * cS * cDH;
  const u16* Vh = Vt + (size_t)bh * cDH * cS;
  // flags are per 64-row q-tile; this wave's rows live in one 64-tile
  const unsigned char* fl = flags + (b << 10) + ((qbase + w * 16) >> 6) * 32;

  // Q fragments (pre-scaled by 1/8), MFMA B operand
  s16x8 qf[2];
  {
    const u16* qp = Qh + (size_t)(qbase + w * 16 + li) * cDH;
    qf[0] = *(const s16x8*)(qp + 8 * g);
    qf[1] = *(const s16x8*)(qp + 32 + 8 * g);
  }
  int srow8 = l >> 3, schunk = l & 7;
  int q_lane = qbase + w * 16 + li;
  int srow = w * 8 + srow8;                       // this lane's staged row
  const u16* kstage = Kh + (size_t)srow * cDH + ((schunk ^ (srow & 7)) * 8);
  const u16* vstage = Vh + (size_t)srow * cS + ((schunk ^ (srow & 7)) * 8);
  u16* kl_dst = &Kl[0][(w * 8) * 64];             // wave-uniform LDS bases
  u16* vl_dst = &Vl[0][(w * 8) * 64];
  const int KSTEP = 64 * cDH;                     // K elems per kt

  // ---- Pass A: row sums of exp(logits); K double-buffered, 1 barrier/kt ----
  gload16(kstage, kl_dst);
  asm volatile("s_waitcnt vmcnt(0)" ::: "memory");
  __builtin_amdgcn_sched_barrier(0);
  __builtin_amdgcn_s_barrier();
  __builtin_amdgcn_sched_barrier(0);
  float racc4[4] = {0.f, 0.f, 0.f, 0.f};         // 4 independent chains
  for (int kt = 0; kt < 32; ++kt) {
    int cur = kt & 1;
    if (kt + 1 < 32)
      gload16(kstage + (size_t)(kt + 1) * KSTEP, kl_dst + (cur ^ 1) * 64 * 64);
    f32x4 acc[4];
    for (int mt = 0; mt < 4; ++mt) acc[mt] = zero4();
    for (int c = 0; c < 2; ++c)
      for (int mt = 0; mt < 4; ++mt) {
        int r = mt * 16 + li;
        s16x8 kf = *(const s16x8*)&Kl[cur][r * 64 + (((c * 4 + g) ^ (r & 7)) * 8)];
        acc[mt] = mfma16(kf, qf[c], acc[mt]);
      }
    bool um = fl[kt] != 0;
    for (int mt = 0; mt < 4; ++mt)
      for (int r = 0; r < 4; ++r) {
        float lv = acc[mt][r];
        if (um) lv += mask[((size_t)b * cS + q_lane) * cS + kt * 64 + mt * 16 + 4 * g + r] * -1e9f;
        racc4[r] += __expf(lv);
      }
    if (kt + 1 < 32) {
      asm volatile("s_waitcnt vmcnt(0)" ::: "memory");
      __builtin_amdgcn_sched_barrier(0);
      __builtin_amdgcn_s_barrier();
      __builtin_amdgcn_sched_barrier(0);
    }
  }
  float racc = (racc4[0] + racc4[1]) + (racc4[2] + racc4[3]);
  racc += __shfl_xor(racc, 16, 64);
  racc += __shfl_xor(racc, 32, 64);
  float lr = __logf(racc);   // log denominator: p = exp(lv - lr)

  // ---- Pass B: K/V double-buffered; stores stay in flight across barriers ----
  f32x4 cacc[4];
  for (int dt = 0; dt < 4; ++dt) cacc[dt] = zero4();
  float* attn_row = attn + (size_t)bh * cS * cS + (size_t)q_lane * cS;
  gload16(kstage, kl_dst);
  gload16(vstage, vl_dst);
  asm volatile("s_waitcnt vmcnt(0)" ::: "memory");
  __builtin_amdgcn_sched_barrier(0);
  __builtin_amdgcn_s_barrier();
  __builtin_amdgcn_sched_barrier(0);
  for (int kt = 0; kt < 32; ++kt) {
    int cur = kt & 1;
    if (kt + 1 < 32) {
      gload16(kstage + (size_t)(kt + 1) * KSTEP, kl_dst + (cur ^ 1) * 64 * 64);
      gload16(vstage + (kt + 1) * 64, vl_dst + (cur ^ 1) * 64 * 64);
    }
    f32x4 acc[4];
    for (int mt = 0; mt < 4; ++mt) acc[mt] = zero4();
    for (int c = 0; c < 2; ++c)
      for (int mt = 0; mt < 4; ++mt) {
        int r = mt * 16 + li;
        s16x8 kf = *(const s16x8*)&Kl[cur][r * 64 + (((c * 4 + g) ^ (r & 7)) * 8)];
        acc[mt] = mfma16(kf, qf[c], acc[mt]);
      }
    bool um = fl[kt] != 0;
    s16x8 pa[2];
    for (int c = 0; c < 2; ++c) {
      union { s16x8 v; unsigned u[4]; } pk;
      f32x4 pvq[2];
      for (int hh = 0; hh < 2; ++hh) {
        int mt = c * 2 + hh;
        for (int r = 0; r < 4; ++r) {
          float lv = acc[mt][r];
          if (um) lv += mask[((size_t)b * cS + q_lane) * cS + kt * 64 + mt * 16 + 4 * g + r] * -1e9f;
          pvq[hh][r] = __expf(lv - lr);
        }
        *(f32x4*)(attn_row + kt * 64 + mt * 16 + 4 * g) = pvq[hh];
      }
      pk.u[0] = cvt_pk_bf16(pvq[0][0], pvq[0][1]);
      pk.u[1] = cvt_pk_bf16(pvq[0][2], pvq[0][3]);
      pk.u[2] = cvt_pk_bf16(pvq[1][0], pvq[1][1]);
      pk.u[3] = cvt_pk_bf16(pvq[1][2], pvq[1][3]);
      pa[c] = pk.v;
    }
    // PV: B-operand V fragments from LDS (row d = dt*16+li), same k-map as P
    for (int c = 0; c < 2; ++c) {
      for (int dt = 0; dt < 4; ++dt) {
        int row = dt * 16 + li;
        const u16* rb = &Vl[cur][row * 64];
        int o0 = (((c * 4 + 0 + (g >> 1)) ^ (li & 7)) * 8) + (g & 1) * 4;
        int o1 = (((c * 4 + 2 + (g >> 1)) ^ (li & 7)) * 8) + (g & 1) * 4;
        union { s16x8 v; u64 qq[2]; } vf;
        vf.qq[0] = *(const u64*)(rb + o0);
        vf.qq[1] = *(const u64*)(rb + o1);
        cacc[dt] = mfma16(pa[c], vf.v, cacc[dt]);
      }
    }
    if (kt + 1 < 32) {
      // wait for the 2 prefetch gloads (older) while the 4 attn stores
      // (younger) remain in flight across the barrier
      asm volatile("s_waitcnt vmcnt(4)" ::: "memory");
      __builtin_amdgcn_sched_barrier(0);
      __builtin_amdgcn_s_barrier();
      __builtin_amdgcn_sched_barrier(0);
    }
  }

  // ctx -> concat layout [b*S+s][h*64+d] bf16 for the output GEMM
  int h = bh & 15;
  for (int dt = 0; dt < 4; ++dt)
    for (int r = 0; r < 4; ++r) {
      int s = qbase + w * 16 + g * 4 + r;
      int d = dt * 16 + li;
      ctx[((size_t)(b * cS + s)) * cD + h * 64 + d] = f2bf(cacc[dt][r]);
    }
}

// ---------------- host launch --------------------------------------------------
extern "C" void kernel_launch(void* const* d_in, const int* in_sizes, int n_in,
                              void* d_out, int out_size, void* d_ws, size_t ws_size,
                              hipStream_t stream) {
  const float* q_in = (const float*)d_in[0];
  const float* k_in = (const float*)d_in[1];
  const float* v_in = (const float*)d_in[2];
  const float* mask = (const float*)d_in[3];
  const float* Wq = (const float*)d_in[4];
  const float* bq = (const float*)d_in[5];
  const float* Wk = (const float*)d_in[6];
  const float* bk = (const float*)d_in[7];
  const float* Wv = (const float*)d_in[8];
  const float* bv = (const float*)d_in[9];
  const float* Wo = (const float*)d_in[10];
  const float* bo = (const float*)d_in[11];

  float* out = (float*)d_out;                       // [B,S,D]
  float* attn = out + (size_t)cB * cS * cD;         // [B,H,S,S]

  // workspace layout (bf16 = 2B): 4 W^T (8MB) + Q + K + Vt + ctx (8MB ea) + flags
  const size_t MATB = (size_t)cB * cS * cD * 2;     // 8,388,608 B
  const size_t WB = (size_t)cD * cD * 2;            // 2,097,152 B
  char* ws = (char*)d_ws;
  u16* WqT = (u16*)(ws);
  u16* WkT = (u16*)(ws + WB);
  u16* WvT = (u16*)(ws + 2 * WB);
  u16* WoT = (u16*)(ws + 3 * WB);
  u16* wsQ  = (u16*)(ws + 4 * WB);
  u16* wsK  = (u16*)(ws + 4 * WB + MATB);
  u16* wsVt = (u16*)(ws + 4 * WB + 2 * MATB);
  u16* wsC  = (u16*)(ws + 4 * WB + 3 * MATB);
  unsigned char* flags = (unsigned char*)(ws + 4 * WB + 4 * MATB);
  const size_t REQUIRED = 4 * WB + 4 * MATB + 2048;
  if (ws_size < REQUIRED) return;  // loud failure (validation will catch)

  // bf16 copies of the X inputs, staged in the (not-yet-written) attn region.
  // attn_kernel later overwrites every byte of this region; qkv_gemm reads them
  // before that in stream order.
  const size_t XE = (size_t)cB * cS * cD;           // 4.19M elems per matrix
  u16* Xq = (u16*)attn;
  u16* Xk = Xq + XE;
  u16* Xv = Xk + XE;

  dim3 tb(32, 8);
  wt4_kernel<<<dim3(32, 32, 4), tb, 0, stream>>>(Wq, Wk, Wv, Wo, WqT, WkT, WvT, WoT);
  maskflag_kernel<<<2048, 256, 0, stream>>>(mask, flags);
  xcvt_kernel<<<dim3((unsigned)(XE / 8 / 256), 1, 3), 256, 0, stream>>>(
      q_in, k_in, v_in, Xq, Xk, Xv);

  qkv_gemm<<<768, 256, 0, stream>>>(Xq, Xk, Xv, WqT, WkT, WvT,
                                    bq, bk, bv, wsQ, wsK, wsVt);

  attn_kernel<<<512, 512, 0, stream>>>(wsQ, wsK, wsVt, mask, flags, attn, wsC);

  out_gemm<<<512, 256, 0, stream>>>(wsC, WoT, bo, out);
}